// Round 20
// baseline (2297.350 us; speedup 1.0000x reference)
//
#include <hip/hip_runtime.h>
#include <math.h>

typedef _Float16 h2_t __attribute__((ext_vector_type(2)));

#define U_ 256
#define NN 128
#define MM 64
#define OUT_ 8
#define CLIPV 20.0f
#define IN_DIM_ 9
#define PP 268
#define B_ 128
#define T_ 130
#define TSTART 65

// ws element counts / byte offsets
#define NWXI 6144       // 2hf * 16wv * 3j * 64ln      (uint4 int8, K=96 pad, kb=q*12+4j)
#define NWH8 16384      // 2hf * 128g4 * 64slot(j*8+q) (uint4 int8, kb=q*32+4j)
#define NWP8 4352       // 68cg * 64slot(j*8+q)        (uint4 int8, FULL width)
#define WXI_OFF 0
#define WH8_OFF 98304
#define WP8_OFF 360448
#define BLH_OFF 430080
#define BPP_OFF 434176
#define COMM_OFF 435264
#define COMM_STRIDE 2176          // hA512|hB512|(unused)|flags|pad
#define COMM_SZ (B_*COMM_STRIDE)
#define PREP_N (NWXI + NWH8 + NWP8 + 256 + 272)

#define WSCALE 256.f
#define HSCALE 127.f
#define OSCALE (1.f/(256.f*127.f))

__device__ __forceinline__ float sigf(float x){ return 1.0f/(1.0f+__expf(-x)); }
__device__ __forceinline__ float splus(float x){ return log1pf(__expf(x)); }
__device__ __forceinline__ float clipf(float x){ return fminf(fmaxf(x,-CLIPV),CLIPV); }

#if defined(__has_builtin)
#if __has_builtin(__builtin_amdgcn_sdot4)
#define SDOT4(a,b,c) __builtin_amdgcn_sdot4((a),(b),(c),false)
#endif
#endif
#ifndef SDOT4
__device__ __forceinline__ int sdot4_sw(int a, int b, int c){
    c += (int)(signed char)(a      ) * (int)(signed char)(b      );
    c += (int)(signed char)(a >> 8 ) * (int)(signed char)(b >> 8 );
    c += (int)(signed char)(a >> 16) * (int)(signed char)(b >> 16);
    c += (a >> 24) * (b >> 24);
    return c;
}
#define SDOT4(a,b,c) sdot4_sw((a),(b),(c))
#endif

#define SD4(u, hw) { \
    a0 = SDOT4((int)(u).x, hw, a0); a1 = SDOT4((int)(u).y, hw, a1); \
    a2 = SDOT4((int)(u).z, hw, a2); a3 = SDOT4((int)(u).w, hw, a3); }
#define SD4P(u, hw) { \
    pa0 = SDOT4((int)(u).x, hw, pa0); pa1 = SDOT4((int)(u).y, hw, pa1); \
    pa2 = SDOT4((int)(u).z, hw, pa2); pa3 = SDOT4((int)(u).w, hw, pa3); }

// encode w -> int8 byte of round(w*256), clamped
__device__ __forceinline__ unsigned ei8(float w){
    int v = (int)rintf(w * WSCALE);
    v = v < -127 ? -127 : (v > 127 ? 127 : v);
    return (unsigned)(v & 0xFF);
}

__device__ __forceinline__ unsigned packi8x4(float a, float b, float c, float d){
    int va = (int)rintf(a * HSCALE); va = va < -127 ? -127 : (va > 127 ? 127 : va);
    int vb = (int)rintf(b * HSCALE); vb = vb < -127 ? -127 : (vb > 127 ? 127 : vb);
    int vc = (int)rintf(c * HSCALE); vc = vc < -127 ? -127 : (vc > 127 ? 127 : vc);
    int vd = (int)rintf(d * HSCALE); vd = vd < -127 ? -127 : (vd > 127 ? 127 : vd);
    return (va & 0xFF) | ((vb & 0xFF) << 8) | ((vc & 0xFF) << 16) | ((vd & 0xFF) << 24);
}

__global__ void prep_kernel(const float* __restrict__ W_x, const float* __restrict__ W_h,
                            const float* __restrict__ W_p, const float* __restrict__ b_lstm,
                            const float* __restrict__ b_p,
                            uint4* __restrict__ wxi8, uint4* __restrict__ whi8,
                            uint4* __restrict__ wpi8,
                            float4* __restrict__ blh, float* __restrict__ bpp)
{
    for (int idx = blockIdx.x*blockDim.x + threadIdx.x; idx < PREP_N; idx += gridDim.x*blockDim.x){
        if (idx < NWXI){
            // int8 wx, ctrl order [r(64), x(9), pad]: [hf][wv][j][ln], kb=q*12+4j (K=96)
            int hf = idx/3072, rem = idx - hf*3072;
            int wv = rem/192, r2 = rem - wv*192, j = r2>>6, ln = r2&63;
            int g4 = wv*8 + (ln>>3), q = ln&7, kb = q*12 + 4*j;
            unsigned c[4];
            #pragma unroll
            for (int g=0; g<4; ++g){
                int col = g*256 + hf*128 + g4;
                unsigned w = 0;
                #pragma unroll
                for (int k=0; k<4; ++k){
                    int K = kb+k;
                    float f = (K<64) ? W_x[(9+K)*1024+col] : (K<73 ? W_x[(K-64)*1024+col] : 0.f);
                    w |= ei8(f) << (8*k);
                }
                c[g] = w;
            }
            wxi8[idx] = make_uint4(c[0],c[1],c[2],c[3]);
        } else if (idx < NWXI + NWH8){
            // int8 W_h: [hf][g4][slot j*8+q], kb=q*32+4j
            int e = idx - NWXI;
            int hf = e>>13, rem = e&8191, g4 = rem>>6, s = rem&63;
            int j = s>>3, q = s&7, kb = q*32 + 4*j;
            unsigned c[4];
            #pragma unroll
            for (int g=0; g<4; ++g){
                int col = g*256 + hf*128 + g4;
                c[g] = ei8(W_h[(kb+0)*1024+col])
                     | (ei8(W_h[(kb+1)*1024+col]) << 8)
                     | (ei8(W_h[(kb+2)*1024+col]) << 16)
                     | (ei8(W_h[(kb+3)*1024+col]) << 24);
            }
            whi8[e] = make_uint4(c[0],c[1],c[2],c[3]);
        } else if (idx < NWXI + NWH8 + NWP8){
            // int8 W_p FULL width: [cg][slot j*8+q], kb=q*32+4j
            int e = idx - NWXI - NWH8;
            int cg = e>>6, s = e&63;
            int j = s>>3, q = s&7, kb = q*32 + 4*j;
            unsigned c[4];
            #pragma unroll
            for (int g=0; g<4; ++g){
                int cl = cg*4+g;
                if (cl < PP){
                    c[g] = ei8(W_p[(kb+0)*PP+cl])
                         | (ei8(W_p[(kb+1)*PP+cl]) << 8)
                         | (ei8(W_p[(kb+2)*PP+cl]) << 16)
                         | (ei8(W_p[(kb+3)*PP+cl]) << 24);
                } else c[g] = 0u;
            }
            wpi8[e] = make_uint4(c[0],c[1],c[2],c[3]);
        } else if (idx < NWXI + NWH8 + NWP8 + 256){
            int u = idx - NWXI - NWH8 - NWP8;
            blh[u] = make_float4(b_lstm[u], b_lstm[256+u], b_lstm[512+u], b_lstm[768+u]);
        } else {
            int j = idx - NWXI - NWH8 - NWP8 - 256;
            bpp[j] = (j < PP) ? b_p[j] : 0.f;
        }
    }
}

__device__ __forceinline__ float decodeP(int rc, float p){
    if (rc < 64 || (rc >= 70 && rc < 134) || rc >= 204) return tanhf(p);
    if (rc >= 140 && rc < 204) return sigf(p);
    return p;
}

__global__ __launch_bounds__(1024,1) void ntm_kernel(
    const float* __restrict__ inputs,
    const float* __restrict__ W_o, const float* __restrict__ b_o,
    const float* __restrict__ r0, const float* __restrict__ w0,
    const uint4* __restrict__ wxi8, const uint4* __restrict__ whi8,
    const uint4* __restrict__ wpi8,
    const float4* __restrict__ blh, const float* __restrict__ bpp,
    char* comm, float* __restrict__ out)
{
    const int bid = blockIdx.x, hf = bid>>7, b = bid&127;
    const int t = threadIdx.x, wv = t>>6, ln = t&63;
    const int g4 = t>>3, q = t&7;

    char* cb = comm + b*COMM_STRIDE;
    volatile float* hOwn = (volatile float*)(cb + hf*512);
    volatile float* hOth = (volatile float*)(cb + (hf^1)*512);
    volatile int*   flg  = (volatile int*)(cb + 2112);   // [f1A,f1B]

    __shared__ uint4 wxL8[3072];         // 48KB pinned int8 wx half (conflict-free)
    __shared__ uint4 whL8[6][1024];      // 96KB pinned int8 W_h slices j=0..5
    __shared__ float4 gpart4[128];
    __shared__ float4 blhL[128];
    __shared__ float hbuf[U_];
    __shared__ float cbuf[128];
    __shared__ unsigned hq[64];          // h as int8 x4 words
    __shared__ unsigned xq[24];          // ctrl [r(16w), x(3w), pad(5w)] int8
    __shared__ float prmS[12];
    __shared__ float scal[12];
    __shared__ float kv[2][MM], ebuf[MM], abuf[MM];
    __shared__ float innr[2][NN], Mn[NN], wgs[2][NN], wtab[2][NN];
    __shared__ float rpart[16][MM];
    __shared__ float jpart[OUT_];

    // Mem in registers: wave wv owns rows 8wv..8wv+7, lane ln = column
    float memR[8];
    #pragma unroll
    for (int k=0; k<8; ++k) memR[k] = 1e-6f;

    // ---- init ----
    for (int i=t; i<3072; i+=1024) wxL8[i] = wxi8[hf*3072 + i];
    for (int i=t; i<6144; i+=1024){
        int j = i>>10, jj = i&1023;
        whL8[j][jj] = whi8[hf*8192 + (jj>>3)*64 + j*8 + (jj&7)];
    }
    if (t < 128){
        gpart4[t] = make_float4(0.f,0.f,0.f,0.f);
        blhL[t] = blh[hf*128+t];
        cbuf[t] = 0.f;
        Mn[t] = 8e-6f;
    }
    if (t < 64) hq[t] = 0u;
    if (t < U_) hbuf[t] = 0.f;
    if (t >= 128 && t < 256){  // wtab = softmax(w0)
        int h = (t-128)>>6, l = t&63;
        float v0 = w0[h*NN + l], v1 = w0[h*NN + l + 64];
        float mx = fmaxf(v0,v1);
        for (int off=32; off>=1; off>>=1) mx = fmaxf(mx, __shfl_xor(mx, off));
        float e0 = __expf(v0-mx), e1 = __expf(v1-mx);
        float s = e0+e1;
        for (int off=32; off>=1; off>>=1) s += __shfl_xor(s, off);
        wtab[h][l] = e0/s; wtab[h][l+64] = e1/s;
    }
    if (t >= 256 && t < 280){   // xq init: [r(16w from tanh r0), x(3w step0), zero]
        int p = t-256;
        if (p < 16){
            xq[p] = packi8x4(tanhf(r0[4*p]), tanhf(r0[4*p+1]), tanhf(r0[4*p+2]), tanhf(r0[4*p+3]));
        } else if (p < 19){
            const float* xin = inputs + b*T_*IN_DIM_;
            int e0 = 4*(p-16);
            float f0 = (e0+0<IN_DIM_) ? xin[e0+0] : 0.f;
            float f1 = (e0+1<IN_DIM_) ? xin[e0+1] : 0.f;
            float f2 = (e0+2<IN_DIM_) ? xin[e0+2] : 0.f;
            float f3 = (e0+3<IN_DIM_) ? xin[e0+3] : 0.f;
            xq[p] = packi8x4(f0,f1,f2,f3);
        } else xq[p] = 0u;
    }
    __syncthreads();

    for (int step=0; step<T_; ++step){
        const int* xqi = (const int*)xq;

        // ---- B: gates = xq . wxL8 (int8 sdot4) + gpart + bias, fused LSTM ----
        {
            const uint4* wb = wxL8 + wv*192;
            int a0=0,a1=0,a2=0,a3=0;
            #pragma unroll
            for (int j=0; j<3; ++j){
                uint4 u = wb[j*64 + ln];
                int xw = xqi[q*3+j];
                SD4(u, xw);
            }
            #pragma unroll
            for (int m=1; m<8; m<<=1){
                a0 += __shfl_xor(a0,m); a1 += __shfl_xor(a1,m);
                a2 += __shfl_xor(a2,m); a3 += __shfl_xor(a3,m);
            }
            if (q==0){
                float4 bb = blhL[g4]; float4 gp = gpart4[g4];
                float gi=a0*OSCALE+bb.x+gp.x, gf=a1*OSCALE+bb.y+gp.y;
                float gg=a2*OSCALE+bb.z+gp.z, go=a3*OSCALE+bb.w+gp.w;
                float c = sigf(gf)*cbuf[g4] + sigf(gi)*tanhf(gg);
                cbuf[g4] = c;
                float h = sigf(go)*tanhf(c);
                hbuf[hf*128+g4] = h;
                hOwn[g4] = h;
            }
        }
        __syncthreads();                          // drains volatile h stores
        if (t==0){
            flg[hf] = step+1;
            while (flg[hf^1] < step+1) __builtin_amdgcn_s_sleep(2);
        }
        __syncthreads();
        // pull partner h; pack int8 h words
        if (t < 128){
            hbuf[(hf^1)*128 + t] = hOth[t];
        } else if (t < 160){
            const int jj = t-128;                  // own half word
            const float* hp = &hbuf[hf*128 + 4*jj];
            hq[hf*32 + jj] = packi8x4(hp[0], hp[1], hp[2], hp[3]);
        } else if (t < 192){
            const int jj = t-160;                  // partner half word (from comm)
            float h0 = hOth[4*jj], h1 = hOth[4*jj+1], h2 = hOth[4*jj+2], h3 = hOth[4*jj+3];
            hq[(hf^1)*32 + jj] = packi8x4(h0, h1, h2, h3);
        }
        __syncthreads();

        const int* hqi = (const int*)hq;

        // ---- FUSED: gpart (6 LDS + 2 streamed) ; params int8 FULL ; jpart ; x-pre ----
        {
            const uint4* wrow = whi8 + hf*8192 + g4*64;
            int a0=0,a1=0,a2=0,a3=0;
            uint4 s6 = wrow[48+q], s7 = wrow[56+q];
            uint4 l0 = whL8[0][t], l1 = whL8[1][t], l2 = whL8[2][t];
            uint4 l3 = whL8[3][t], l4 = whL8[4][t], l5 = whL8[5][t];
            int hw0=hqi[q*8+0], hw1=hqi[q*8+1], hw2=hqi[q*8+2], hw3=hqi[q*8+3];
            int hw4=hqi[q*8+4], hw5=hqi[q*8+5], hw6=hqi[q*8+6], hw7=hqi[q*8+7];
            SD4(l0, hw0); SD4(l1, hw1);
            SD4(l2, hw2); SD4(l3, hw3);
            SD4(l4, hw4); SD4(l5, hw5);
            SD4(s6, hw6); SD4(s7, hw7);
            #pragma unroll
            for (int m=1; m<8; m<<=1){
                a0 += __shfl_xor(a0,m); a1 += __shfl_xor(a1,m);
                a2 += __shfl_xor(a2,m); a3 += __shfl_xor(a3,m);
            }
            if (q==0) gpart4[g4] = make_float4(a0*OSCALE, a1*OSCALE, a2*OSCALE, a3*OSCALE);
        }
        if (t < 544){
            const int cg = t>>3, qq = t&7;
            const uint4* wrow = wpi8 + cg*64;
            int pa0=0, pa1=0, pa2=0, pa3=0;
            uint4 u0=wrow[0*8+qq], u1=wrow[1*8+qq], u2=wrow[2*8+qq], u3=wrow[3*8+qq];
            uint4 u4=wrow[4*8+qq], u5=wrow[5*8+qq], u6=wrow[6*8+qq], u7=wrow[7*8+qq];
            int hw0=hqi[qq*8+0], hw1=hqi[qq*8+1], hw2=hqi[qq*8+2], hw3=hqi[qq*8+3];
            int hw4=hqi[qq*8+4], hw5=hqi[qq*8+5], hw6=hqi[qq*8+6], hw7=hqi[qq*8+7];
            SD4P(u0, hw0); SD4P(u1, hw1);
            SD4P(u2, hw2); SD4P(u3, hw3);
            SD4P(u4, hw4); SD4P(u5, hw5);
            SD4P(u6, hw6); SD4P(u7, hw7);
            #pragma unroll
            for (int m=1; m<8; m<<=1){
                pa0 += __shfl_xor(pa0,m); pa1 += __shfl_xor(pa1,m);
                pa2 += __shfl_xor(pa2,m); pa3 += __shfl_xor(pa3,m);
            }
            if (qq==0){
                #pragma unroll
                for (int j=0; j<4; ++j){
                    int aj = (j==0)?pa0:((j==1)?pa1:((j==2)?pa2:pa3));
                    int cl = cg*4+j;
                    if (cl < PP){
                        float pv = clipf(aj*OSCALE + bpp[cl]);
                        float dv = decodeP(cl, pv);
                        if (cl < 64) kv[0][cl] = dv;
                        else if (cl < 70) prmS[cl-64] = dv;
                        else if (cl < 134) kv[1][cl-70] = dv;
                        else if (cl < 140) prmS[6+cl-134] = dv;
                        else if (cl < 204) ebuf[cl-140] = dv;
                        else abuf[cl-204] = dv;
                    }
                }
            }
        } else if (t >= 800 && t < 928){
            const int o = (t-800)>>4, l16 = (t-800)&15;
            float s = 0.f;
            #pragma unroll
            for (int j=0; j<16; ++j){
                const int i = l16 + (j<<4);
                s = fmaf(hbuf[i], W_o[i*OUT_ + o], s);
            }
            s += __shfl_xor(s,1); s += __shfl_xor(s,2);
            s += __shfl_xor(s,4); s += __shfl_xor(s,8);
            if (l16==0) jpart[o] = s;
        } else if (t >= 928 && t < 931){
            if (step+1 < T_){
                const int p = t-928;                 // xq words 16..18 (x part)
                const float* xin = inputs + (b*T_ + step+1)*IN_DIM_;
                int e0 = 4*p;
                float f0 = (e0+0<IN_DIM_) ? xin[e0+0] : 0.f;
                float f1 = (e0+1<IN_DIM_) ? xin[e0+1] : 0.f;
                float f2 = (e0+2<IN_DIM_) ? xin[e0+2] : 0.f;
                float f3 = (e0+3<IN_DIM_) ? xin[e0+3] : 0.f;
                xq[16+p] = packi8x4(f0,f1,f2,f3);
            }
        }
        __syncthreads();

        // ---- F: innr + Mn via wave butterfly over register Mem + scal decode ----
        {
            float k0l = kv[0][ln], k1l = kv[1][ln];
            #pragma unroll
            for (int k=0; k<8; ++k){
                const int n = wv*8 + k;
                float m = memR[k];
                float s0 = k0l*m, s1 = k1l*m, s2 = m*m;
                #pragma unroll
                for (int off=32; off>=1; off>>=1){
                    s0 += __shfl_xor(s0,off);
                    s1 += __shfl_xor(s1,off);
                    s2 += __shfl_xor(s2,off);
                }
                if (ln==0){ innr[0][n]=s0; innr[1][n]=s1; Mn[n]=sqrtf(s2); }
            }
        }
        if (t < 2){
            const int h = t;
            const float* ps = prmS + 6*h;
            scal[h]   = splus(ps[0]);
            scal[2+h] = sigf(ps[1]);
            float p0=ps[2], p1=ps[3], p2=ps[4];
            float mx = fmaxf(p0, fmaxf(p1, p2));
            float e0=__expf(p0-mx), e1=__expf(p1-mx), e2=__expf(p2-mx);
            float s = e0+e1+e2;
            scal[6+3*h]=e0/s; scal[7+3*h]=e1/s; scal[8+3*h]=e2/s;
            scal[4+h] = 1.f + splus(ps[5]);
        }
        __syncthreads();

        // ---- G: key norm + content softmax + interp + shift + sharpen ----
        if (t < 128){
            const int h = t>>6, l = ln;
            float kvl = kv[h][l];
            float kn2 = kvl*kvl;
            for (int off=32; off>=1; off>>=1) kn2 += __shfl_xor(kn2, off);
            float kn = sqrtf(kn2);
            float beta = scal[h], g = scal[2+h];
            float bk0 = beta * innr[h][l]   /(kn*Mn[l]   +1e-8f);
            float bk1 = beta * innr[h][l+64]/(kn*Mn[l+64]+1e-8f);
            float mx = fmaxf(bk0,bk1);
            for (int off=32; off>=1; off>>=1) mx = fmaxf(mx, __shfl_xor(mx, off));
            float e0=__expf(bk0-mx), e1=__expf(bk1-mx);
            float s=e0+e1;
            for (int off=32; off>=1; off>>=1) s += __shfl_xor(s, off);
            float wc0=e0/s, wc1=e1/s;
            wgs[h][l]    = g*wc0 + (1.f-g)*wtab[h][l];
            wgs[h][l+64] = g*wc1 + (1.f-g)*wtab[h][l+64];
            float gamma = scal[4+h];
            float s0=scal[6+3*h], s1=scal[7+3*h], s2=scal[8+3*h];
            const int n0=l, n1=l+64;
            float wt0 = s0*wgs[h][(n0+1)&127] + s1*wgs[h][n0] + s2*wgs[h][(n0+127)&127];
            float wt1 = s0*wgs[h][(n1+1)&127] + s1*wgs[h][n1] + s2*wgs[h][(n1+127)&127];
            float wp0 = __powf(wt0, gamma), wp1 = __powf(wt1, gamma);
            float ss = wp0+wp1;
            for (int off=32; off>=1; off>>=1) ss += __shfl_xor(ss, off);
            float inv = 1.0f/(ss+1e-8f);
            wtab[h][n0] = wp0*inv; wtab[h][n1] = wp1*inv;
        }
        __syncthreads();

        // ---- H: memory write (registers) + fused read-head partials ----
        {
            const float el = ebuf[ln], al = abuf[ln];
            float racc = 0.f;
            #pragma unroll
            for (int k=0; k<8; ++k){
                const int n = wv*8 + k;
                float ww = wtab[1][n];
                float wr = wtab[0][n];
                float v = memR[k]*(1.0f - ww*el) + ww*al;
                memR[k] = v;
                racc = fmaf(wr, v, racc);
            }
            rpart[wv][ln] = racc;
        }
        __syncthreads();

        // ---- J: r finalize + output (hf==0 writes) + xq r-pack ----
        if (t < 512){
            const int o = wv;
            float rm = 0.f;
            #pragma unroll
            for (int k=0; k<16; ++k) rm += rpart[k][ln];
            float s = rm * W_o[(U_+ln)*OUT_ + o];
            for (int off=32; off>=1; off>>=1) s += __shfl_xor(s, off);
            if (ln==0 && hf==0 && step>=TSTART){
                float logit = clipf(s + jpart[o] + b_o[o]);
                out[((b*(T_-TSTART)) + (step-TSTART))*OUT_ + o] = sigf(logit);
            }
        } else if (t < 576){
            float rm = 0.f;
            #pragma unroll
            for (int k=0; k<16; ++k) rm += rpart[k][ln];
            float r1 = __shfl_down(rm, 1);
            float r2 = __shfl_down(rm, 2);
            float r3 = __shfl_down(rm, 3);
            if (!(ln&3)) xq[ln>>2] = packi8x4(rm, r1, r2, r3);
        }
        __syncthreads();
    }
}

extern "C" void kernel_launch(void* const* d_in, const int* in_sizes, int n_in,
                              void* d_out, int out_size, void* d_ws, size_t ws_size,
                              hipStream_t stream) {
    const float* inputs = (const float*)d_in[0];
    const float* W_x    = (const float*)d_in[1];
    const float* W_h    = (const float*)d_in[2];
    const float* b_lstm = (const float*)d_in[3];
    const float* W_p    = (const float*)d_in[4];
    const float* b_p    = (const float*)d_in[5];
    const float* W_o    = (const float*)d_in[6];
    const float* b_o    = (const float*)d_in[7];
    const float* r0     = (const float*)d_in[8];
    const float* w0     = (const float*)d_in[9];
    float* out = (float*)d_out;

    char* ws = (char*)d_ws;
    uint4*  wxi = (uint4*)(ws + WXI_OFF);
    uint4*  wh8 = (uint4*)(ws + WH8_OFF);
    uint4*  wp8 = (uint4*)(ws + WP8_OFF);
    float4* blh = (float4*)(ws + BLH_OFF);
    float*  bpp = (float*)(ws + BPP_OFF);
    char*   comm = ws + COMM_OFF;

    hipMemsetAsync(comm, 0, COMM_SZ, stream);
    prep_kernel<<<512, 256, 0, stream>>>(W_x, W_h, W_p, b_lstm, b_p, wxi, wh8, wp8, blh, bpp);
    ntm_kernel<<<2*B_, 1024, 0, stream>>>(inputs, W_o, b_o, r0, w0,
                                          wxi, wh8, wp8, blh, bpp, comm, out);
}

// Round 21
// 1567.469 us; speedup vs baseline: 1.4656x; 1.4656x over previous
//
#include <hip/hip_runtime.h>
#include <math.h>

typedef _Float16 h2_t __attribute__((ext_vector_type(2)));

#define U_ 256
#define NN 128
#define MM 64
#define OUT_ 8
#define CLIPV 20.0f
#define IN_DIM_ 9
#define PP 268
#define B_ 128
#define T_ 130
#define TSTART 65

// ws element counts / byte offsets
#define NWXI 6144       // 2hf * 16wv * 3j * 64ln      (uint4 int8, K=96 pad, kb=q*12+4j)
#define NWH8 16384      // 2hf * 128g4 * 64slot(j*8+q) (uint4 int8, kb=q*32+4j)
#define NWP8 4352       // 68cg * 64slot(j*8+q)        (uint4 int8, FULL width)
#define WXI_OFF 0
#define WH8_OFF 98304
#define WP8_OFF 360448
#define BLH_OFF 430080
#define BPP_OFF 434176
#define COMM_OFF 435264
#define COMM_STRIDE 2176          // hA512|hB512|(unused)|flags|pad
#define COMM_SZ (B_*COMM_STRIDE)
#define PREP_N (NWXI + NWH8 + NWP8 + 256 + 272)

#define WSCALE 256.f
#define HSCALE 127.f
#define OSCALE (1.f/(256.f*127.f))

__device__ __forceinline__ float sigf(float x){ return 1.0f/(1.0f+__expf(-x)); }
__device__ __forceinline__ float splus(float x){ return log1pf(__expf(x)); }
__device__ __forceinline__ float clipf(float x){ return fminf(fmaxf(x,-CLIPV),CLIPV); }

#if defined(__has_builtin)
#if __has_builtin(__builtin_amdgcn_sdot4)
#define SDOT4(a,b,c) __builtin_amdgcn_sdot4((a),(b),(c),false)
#endif
#endif
#ifndef SDOT4
__device__ __forceinline__ int sdot4_sw(int a, int b, int c){
    c += (int)(signed char)(a      ) * (int)(signed char)(b      );
    c += (int)(signed char)(a >> 8 ) * (int)(signed char)(b >> 8 );
    c += (int)(signed char)(a >> 16) * (int)(signed char)(b >> 16);
    c += (a >> 24) * (b >> 24);
    return c;
}
#define SDOT4(a,b,c) sdot4_sw((a),(b),(c))
#endif

#define SD4(u, hw) { \
    a0 = SDOT4((int)(u).x, hw, a0); a1 = SDOT4((int)(u).y, hw, a1); \
    a2 = SDOT4((int)(u).z, hw, a2); a3 = SDOT4((int)(u).w, hw, a3); }
#define SD4P(u, hw) { \
    pa0 = SDOT4((int)(u).x, hw, pa0); pa1 = SDOT4((int)(u).y, hw, pa1); \
    pa2 = SDOT4((int)(u).z, hw, pa2); pa3 = SDOT4((int)(u).w, hw, pa3); }

// encode w -> int8 byte of round(w*256), clamped
__device__ __forceinline__ unsigned ei8(float w){
    int v = (int)rintf(w * WSCALE);
    v = v < -127 ? -127 : (v > 127 ? 127 : v);
    return (unsigned)(v & 0xFF);
}

__device__ __forceinline__ unsigned packi8x4(float a, float b, float c, float d){
    int va = (int)rintf(a * HSCALE); va = va < -127 ? -127 : (va > 127 ? 127 : va);
    int vb = (int)rintf(b * HSCALE); vb = vb < -127 ? -127 : (vb > 127 ? 127 : vb);
    int vc = (int)rintf(c * HSCALE); vc = vc < -127 ? -127 : (vc > 127 ? 127 : vc);
    int vd = (int)rintf(d * HSCALE); vd = vd < -127 ? -127 : (vd > 127 ? 127 : vd);
    return (va & 0xFF) | ((vb & 0xFF) << 8) | ((vc & 0xFF) << 16) | ((vd & 0xFF) << 24);
}

__global__ void prep_kernel(const float* __restrict__ W_x, const float* __restrict__ W_h,
                            const float* __restrict__ W_p, const float* __restrict__ b_lstm,
                            const float* __restrict__ b_p,
                            uint4* __restrict__ wxi8, uint4* __restrict__ whi8,
                            uint4* __restrict__ wpi8,
                            float4* __restrict__ blh, float* __restrict__ bpp)
{
    for (int idx = blockIdx.x*blockDim.x + threadIdx.x; idx < PREP_N; idx += gridDim.x*blockDim.x){
        if (idx < NWXI){
            // int8 wx, ctrl order [r(64), x(9), pad]: [hf][wv][j][ln], kb=q*12+4j (K=96)
            int hf = idx/3072, rem = idx - hf*3072;
            int wv = rem/192, r2 = rem - wv*192, j = r2>>6, ln = r2&63;
            int g4 = wv*8 + (ln>>3), q = ln&7, kb = q*12 + 4*j;
            unsigned c[4];
            #pragma unroll
            for (int g=0; g<4; ++g){
                int col = g*256 + hf*128 + g4;
                unsigned w = 0;
                #pragma unroll
                for (int k=0; k<4; ++k){
                    int K = kb+k;
                    float f = (K<64) ? W_x[(9+K)*1024+col] : (K<73 ? W_x[(K-64)*1024+col] : 0.f);
                    w |= ei8(f) << (8*k);
                }
                c[g] = w;
            }
            wxi8[idx] = make_uint4(c[0],c[1],c[2],c[3]);
        } else if (idx < NWXI + NWH8){
            // int8 W_h: [hf][g4][slot j*8+q], kb=q*32+4j
            int e = idx - NWXI;
            int hf = e>>13, rem = e&8191, g4 = rem>>6, s = rem&63;
            int j = s>>3, q = s&7, kb = q*32 + 4*j;
            unsigned c[4];
            #pragma unroll
            for (int g=0; g<4; ++g){
                int col = g*256 + hf*128 + g4;
                c[g] = ei8(W_h[(kb+0)*1024+col])
                     | (ei8(W_h[(kb+1)*1024+col]) << 8)
                     | (ei8(W_h[(kb+2)*1024+col]) << 16)
                     | (ei8(W_h[(kb+3)*1024+col]) << 24);
            }
            whi8[e] = make_uint4(c[0],c[1],c[2],c[3]);
        } else if (idx < NWXI + NWH8 + NWP8){
            // int8 W_p FULL width: [cg][slot j*8+q], kb=q*32+4j
            int e = idx - NWXI - NWH8;
            int cg = e>>6, s = e&63;
            int j = s>>3, q = s&7, kb = q*32 + 4*j;
            unsigned c[4];
            #pragma unroll
            for (int g=0; g<4; ++g){
                int cl = cg*4+g;
                if (cl < PP){
                    c[g] = ei8(W_p[(kb+0)*PP+cl])
                         | (ei8(W_p[(kb+1)*PP+cl]) << 8)
                         | (ei8(W_p[(kb+2)*PP+cl]) << 16)
                         | (ei8(W_p[(kb+3)*PP+cl]) << 24);
                } else c[g] = 0u;
            }
            wpi8[e] = make_uint4(c[0],c[1],c[2],c[3]);
        } else if (idx < NWXI + NWH8 + NWP8 + 256){
            int u = idx - NWXI - NWH8 - NWP8;
            blh[u] = make_float4(b_lstm[u], b_lstm[256+u], b_lstm[512+u], b_lstm[768+u]);
        } else {
            int j = idx - NWXI - NWH8 - NWP8 - 256;
            bpp[j] = (j < PP) ? b_p[j] : 0.f;
        }
    }
}

__device__ __forceinline__ float decodeP(int rc, float p){
    if (rc < 64 || (rc >= 70 && rc < 134) || rc >= 204) return tanhf(p);
    if (rc >= 140 && rc < 204) return sigf(p);
    return p;
}

__global__ __launch_bounds__(1024,1) void ntm_kernel(
    const float* __restrict__ inputs,
    const float* __restrict__ W_o, const float* __restrict__ b_o,
    const float* __restrict__ r0, const float* __restrict__ w0,
    const uint4* __restrict__ wxi8, const uint4* __restrict__ whi8,
    const uint4* __restrict__ wpi8,
    const float4* __restrict__ blh, const float* __restrict__ bpp,
    char* comm, float* __restrict__ out)
{
    const int bid = blockIdx.x, hf = bid>>7, b = bid&127;
    const int t = threadIdx.x, wv = t>>6, ln = t&63;
    const int g4 = t>>3, q = t&7;

    char* cb = comm + b*COMM_STRIDE;
    volatile float* hOwn = (volatile float*)(cb + hf*512);
    volatile float* hOth = (volatile float*)(cb + (hf^1)*512);
    volatile int*   flg  = (volatile int*)(cb + 2112);   // [f1A,f1B]

    __shared__ uint4 wxL8[3072];         // 48KB pinned int8 wx half (conflict-free)
    __shared__ uint4 whL8[4][1024];      // 64KB pinned int8 W_h slices j=0..3
    __shared__ float Mem[NN][MM+1];
    __shared__ float4 gpart4[128];
    __shared__ float4 blhL[128];
    __shared__ float hbuf[U_];
    __shared__ float cbuf[128];
    __shared__ unsigned hq[64];          // h as int8 x4 words
    __shared__ unsigned xq[24];          // ctrl [r(16w), x(3w), pad(5w)] int8
    __shared__ float prmS[12];
    __shared__ float scal[12];
    __shared__ float kv[2][MM], ebuf[MM], abuf[MM];
    __shared__ float innr[2][NN], Mn[NN], wgs[2][NN], wtab[2][NN];
    __shared__ float rpart[16][MM];
    __shared__ float jpart[OUT_];

    // ---- init ----
    for (int i=t; i<3072; i+=1024) wxL8[i] = wxi8[hf*3072 + i];
    for (int i=t; i<4096; i+=1024){
        int j = i>>10, jj = i&1023;
        whL8[j][jj] = whi8[hf*8192 + (jj>>3)*64 + j*8 + (jj&7)];
    }
    for (int i=t; i<NN*MM; i+=1024) Mem[i>>6][i&63] = 1e-6f;
    if (t < 128){
        gpart4[t] = make_float4(0.f,0.f,0.f,0.f);
        blhL[t] = blh[hf*128+t];
        cbuf[t] = 0.f;
        Mn[t] = 8e-6f;
    }
    if (t < 64) hq[t] = 0u;
    if (t < U_) hbuf[t] = 0.f;
    if (t >= 128 && t < 256){  // wtab = softmax(w0)
        int h = (t-128)>>6, l = t&63;
        float v0 = w0[h*NN + l], v1 = w0[h*NN + l + 64];
        float mx = fmaxf(v0,v1);
        for (int off=32; off>=1; off>>=1) mx = fmaxf(mx, __shfl_xor(mx, off));
        float e0 = __expf(v0-mx), e1 = __expf(v1-mx);
        float s = e0+e1;
        for (int off=32; off>=1; off>>=1) s += __shfl_xor(s, off);
        wtab[h][l] = e0/s; wtab[h][l+64] = e1/s;
    }
    if (t >= 256 && t < 280){   // xq init: [r(16w from tanh r0), x(3w step0), zero]
        int p = t-256;
        if (p < 16){
            xq[p] = packi8x4(tanhf(r0[4*p]), tanhf(r0[4*p+1]), tanhf(r0[4*p+2]), tanhf(r0[4*p+3]));
        } else if (p < 19){
            const float* xin = inputs + b*T_*IN_DIM_;
            int e0 = 4*(p-16);
            float f0 = (e0+0<IN_DIM_) ? xin[e0+0] : 0.f;
            float f1 = (e0+1<IN_DIM_) ? xin[e0+1] : 0.f;
            float f2 = (e0+2<IN_DIM_) ? xin[e0+2] : 0.f;
            float f3 = (e0+3<IN_DIM_) ? xin[e0+3] : 0.f;
            xq[p] = packi8x4(f0,f1,f2,f3);
        } else xq[p] = 0u;
    }
    __syncthreads();

    const uint4* wrowG = whi8 + hf*8192 + g4*64;

    for (int step=0; step<T_; ++step){
        const int* xqi = (const int*)xq;

        // ---- pre-issue the 4 streamed gpart loads (addresses loop-invariant):
        //      they drain under B + sync1; register-dest loads need no barrier drain
        uint4 s4 = wrowG[32+q], s5 = wrowG[40+q], s6 = wrowG[48+q], s7 = wrowG[56+q];

        // ---- B: gates = xq . wxL8 (int8 sdot4) + gpart + bias, fused LSTM ----
        {
            const uint4* wb = wxL8 + wv*192;
            int a0=0,a1=0,a2=0,a3=0;
            #pragma unroll
            for (int j=0; j<3; ++j){
                uint4 u = wb[j*64 + ln];
                int xw = xqi[q*3+j];
                SD4(u, xw);
            }
            #pragma unroll
            for (int m=1; m<8; m<<=1){
                a0 += __shfl_xor(a0,m); a1 += __shfl_xor(a1,m);
                a2 += __shfl_xor(a2,m); a3 += __shfl_xor(a3,m);
            }
            if (q==0){
                float4 bb = blhL[g4]; float4 gp = gpart4[g4];
                float gi=a0*OSCALE+bb.x+gp.x, gf=a1*OSCALE+bb.y+gp.y;
                float gg=a2*OSCALE+bb.z+gp.z, go=a3*OSCALE+bb.w+gp.w;
                float c = sigf(gf)*cbuf[g4] + sigf(gi)*tanhf(gg);
                cbuf[g4] = c;
                float h = sigf(go)*tanhf(c);
                hbuf[hf*128+g4] = h;
                hOwn[g4] = h;
            }
        }
        __syncthreads();                          // drains volatile h stores
        if (t==0){
            flg[hf] = step+1;
            while (flg[hf^1] < step+1) __builtin_amdgcn_s_sleep(2);
        }
        __syncthreads();
        // pull partner h; pack int8 h words
        if (t < 128){
            hbuf[(hf^1)*128 + t] = hOth[t];
        } else if (t < 160){
            const int jj = t-128;                  // own half word
            const float* hp = &hbuf[hf*128 + 4*jj];
            hq[hf*32 + jj] = packi8x4(hp[0], hp[1], hp[2], hp[3]);
        } else if (t < 192){
            const int jj = t-160;                  // partner half word (from comm)
            float h0 = hOth[4*jj], h1 = hOth[4*jj+1], h2 = hOth[4*jj+2], h3 = hOth[4*jj+3];
            hq[(hf^1)*32 + jj] = packi8x4(h0, h1, h2, h3);
        }
        __syncthreads();

        const int* hqi = (const int*)hq;

        // ---- FUSED: gpart (4 LDS + 4 pre-issued) ; params int8 FULL ; Mn ; jpart ; x-pre ----
        {
            int a0=0,a1=0,a2=0,a3=0;
            uint4 l0 = whL8[0][t], l1 = whL8[1][t], l2 = whL8[2][t], l3 = whL8[3][t];
            int hw0=hqi[q*8+0], hw1=hqi[q*8+1], hw2=hqi[q*8+2], hw3=hqi[q*8+3];
            int hw4=hqi[q*8+4], hw5=hqi[q*8+5], hw6=hqi[q*8+6], hw7=hqi[q*8+7];
            SD4(l0, hw0); SD4(l1, hw1);
            SD4(l2, hw2); SD4(l3, hw3);
            SD4(s4, hw4); SD4(s5, hw5);
            SD4(s6, hw6); SD4(s7, hw7);
            #pragma unroll
            for (int m=1; m<8; m<<=1){
                a0 += __shfl_xor(a0,m); a1 += __shfl_xor(a1,m);
                a2 += __shfl_xor(a2,m); a3 += __shfl_xor(a3,m);
            }
            if (q==0) gpart4[g4] = make_float4(a0*OSCALE, a1*OSCALE, a2*OSCALE, a3*OSCALE);
        }
        if (t < 544){
            const int cg = t>>3, qq = t&7;
            const uint4* wrow = wpi8 + cg*64;
            int pa0=0, pa1=0, pa2=0, pa3=0;
            uint4 u0=wrow[0*8+qq], u1=wrow[1*8+qq], u2=wrow[2*8+qq], u3=wrow[3*8+qq];
            uint4 u4=wrow[4*8+qq], u5=wrow[5*8+qq], u6=wrow[6*8+qq], u7=wrow[7*8+qq];
            int hw0=hqi[qq*8+0], hw1=hqi[qq*8+1], hw2=hqi[qq*8+2], hw3=hqi[qq*8+3];
            int hw4=hqi[qq*8+4], hw5=hqi[qq*8+5], hw6=hqi[qq*8+6], hw7=hqi[qq*8+7];
            SD4P(u0, hw0); SD4P(u1, hw1);
            SD4P(u2, hw2); SD4P(u3, hw3);
            SD4P(u4, hw4); SD4P(u5, hw5);
            SD4P(u6, hw6); SD4P(u7, hw7);
            #pragma unroll
            for (int m=1; m<8; m<<=1){
                pa0 += __shfl_xor(pa0,m); pa1 += __shfl_xor(pa1,m);
                pa2 += __shfl_xor(pa2,m); pa3 += __shfl_xor(pa3,m);
            }
            if (qq==0){
                #pragma unroll
                for (int j=0; j<4; ++j){
                    int aj = (j==0)?pa0:((j==1)?pa1:((j==2)?pa2:pa3));
                    int cl = cg*4+j;
                    if (cl < PP){
                        float pv = clipf(aj*OSCALE + bpp[cl]);
                        float dv = decodeP(cl, pv);
                        if (cl < 64) kv[0][cl] = dv;
                        else if (cl < 70) prmS[cl-64] = dv;
                        else if (cl < 134) kv[1][cl-70] = dv;
                        else if (cl < 140) prmS[6+cl-134] = dv;
                        else if (cl < 204) ebuf[cl-140] = dv;
                        else abuf[cl-204] = dv;
                    }
                }
            }
        } else if (t < 800){
            const int idx = t-544, n = idx>>1, m0 = (idx&1)*32;
            float s = 0.f;
            #pragma unroll 8
            for (int m=m0; m<m0+32; ++m){ float v=Mem[n][m]; s=fmaf(v,v,s); }
            s += __shfl_xor(s,1);
            if (!(idx&1)) Mn[n] = sqrtf(s);
        } else if (t < 928){
            const int o = (t-800)>>4, l16 = (t-800)&15;
            float s = 0.f;
            #pragma unroll
            for (int j=0; j<16; ++j){
                const int i = l16 + (j<<4);
                s = fmaf(hbuf[i], W_o[i*OUT_ + o], s);
            }
            s += __shfl_xor(s,1); s += __shfl_xor(s,2);
            s += __shfl_xor(s,4); s += __shfl_xor(s,8);
            if (l16==0) jpart[o] = s;
        } else if (t < 931){
            if (step+1 < T_){
                const int p = t-928;                 // xq words 16..18 (x part)
                const float* xin = inputs + (b*T_ + step+1)*IN_DIM_;
                int e0 = 4*p;
                float f0 = (e0+0<IN_DIM_) ? xin[e0+0] : 0.f;
                float f1 = (e0+1<IN_DIM_) ? xin[e0+1] : 0.f;
                float f2 = (e0+2<IN_DIM_) ? xin[e0+2] : 0.f;
                float f3 = (e0+3<IN_DIM_) ? xin[e0+3] : 0.f;
                xq[16+p] = packi8x4(f0,f1,f2,f3);
            }
        }
        __syncthreads();

        // ---- F: inner products + scal decode ----
        {
            const int h = t>>9, n = (t>>2)&127, qm = t&3, m0 = qm*16;
            float s = 0.f;
            #pragma unroll 8
            for (int m=m0; m<m0+16; ++m) s = fmaf(kv[h][m], Mem[n][m], s);
            s += __shfl_xor(s,1); s += __shfl_xor(s,2);
            if (qm==0) innr[h][n] = s;
        }
        if (t < 2){
            const int h = t;
            const float* ps = prmS + 6*h;
            scal[h]   = splus(ps[0]);
            scal[2+h] = sigf(ps[1]);
            float p0=ps[2], p1=ps[3], p2=ps[4];
            float mx = fmaxf(p0, fmaxf(p1, p2));
            float e0=__expf(p0-mx), e1=__expf(p1-mx), e2=__expf(p2-mx);
            float s = e0+e1+e2;
            scal[6+3*h]=e0/s; scal[7+3*h]=e1/s; scal[8+3*h]=e2/s;
            scal[4+h] = 1.f + splus(ps[5]);
        }
        __syncthreads();

        // ---- G: key norm + content softmax + interp + shift + sharpen ----
        if (t < 128){
            const int h = t>>6, l = ln;
            float kvl = kv[h][l];
            float kn2 = kvl*kvl;
            for (int off=32; off>=1; off>>=1) kn2 += __shfl_xor(kn2, off);
            float kn = sqrtf(kn2);
            float beta = scal[h], g = scal[2+h];
            float bk0 = beta * innr[h][l]   /(kn*Mn[l]   +1e-8f);
            float bk1 = beta * innr[h][l+64]/(kn*Mn[l+64]+1e-8f);
            float mx = fmaxf(bk0,bk1);
            for (int off=32; off>=1; off>>=1) mx = fmaxf(mx, __shfl_xor(mx, off));
            float e0=__expf(bk0-mx), e1=__expf(bk1-mx);
            float s=e0+e1;
            for (int off=32; off>=1; off>>=1) s += __shfl_xor(s, off);
            float wc0=e0/s, wc1=e1/s;
            wgs[h][l]    = g*wc0 + (1.f-g)*wtab[h][l];
            wgs[h][l+64] = g*wc1 + (1.f-g)*wtab[h][l+64];
            float gamma = scal[4+h];
            float s0=scal[6+3*h], s1=scal[7+3*h], s2=scal[8+3*h];
            const int n0=l, n1=l+64;
            float wt0 = s0*wgs[h][(n0+1)&127] + s1*wgs[h][n0] + s2*wgs[h][(n0+127)&127];
            float wt1 = s0*wgs[h][(n1+1)&127] + s1*wgs[h][n1] + s2*wgs[h][(n1+127)&127];
            float wp0 = __powf(wt0, gamma), wp1 = __powf(wt1, gamma);
            float ss = wp0+wp1;
            for (int off=32; off>=1; off>>=1) ss += __shfl_xor(ss, off);
            float inv = 1.0f/(ss+1e-8f);
            wtab[h][n0] = wp0*inv; wtab[h][n1] = wp1*inv;
        }
        __syncthreads();

        // ---- H: memory write + fused read-head partials ----
        {
            const float el = ebuf[ln], al = abuf[ln];
            const int n0 = wv*8;
            float racc = 0.f;
            #pragma unroll
            for (int k=0; k<8; ++k){
                const int n = n0+k;
                float ww = wtab[1][n];
                float wr = wtab[0][n];
                float v = Mem[n][ln]*(1.0f - ww*el) + ww*al;
                Mem[n][ln] = v;
                racc = fmaf(wr, v, racc);
            }
            rpart[wv][ln] = racc;
        }
        __syncthreads();

        // ---- J: r finalize + output (hf==0 writes) + xq r-pack ----
        if (t < 512){
            const int o = wv;
            float rm = 0.f;
            #pragma unroll
            for (int k=0; k<16; ++k) rm += rpart[k][ln];
            float s = rm * W_o[(U_+ln)*OUT_ + o];
            for (int off=32; off>=1; off>>=1) s += __shfl_xor(s, off);
            if (ln==0 && hf==0 && step>=TSTART){
                float logit = clipf(s + jpart[o] + b_o[o]);
                out[((b*(T_-TSTART)) + (step-TSTART))*OUT_ + o] = sigf(logit);
            }
        } else if (t < 576){
            float rm = 0.f;
            #pragma unroll
            for (int k=0; k<16; ++k) rm += rpart[k][ln];
            float r1 = __shfl_down(rm, 1);
            float r2 = __shfl_down(rm, 2);
            float r3 = __shfl_down(rm, 3);
            if (!(ln&3)) xq[ln>>2] = packi8x4(rm, r1, r2, r3);
        }
        __syncthreads();
    }
}

extern "C" void kernel_launch(void* const* d_in, const int* in_sizes, int n_in,
                              void* d_out, int out_size, void* d_ws, size_t ws_size,
                              hipStream_t stream) {
    const float* inputs = (const float*)d_in[0];
    const float* W_x    = (const float*)d_in[1];
    const float* W_h    = (const float*)d_in[2];
    const float* b_lstm = (const float*)d_in[3];
    const float* W_p    = (const float*)d_in[4];
    const float* b_p    = (const float*)d_in[5];
    const float* W_o    = (const float*)d_in[6];
    const float* b_o    = (const float*)d_in[7];
    const float* r0     = (const float*)d_in[8];
    const float* w0     = (const float*)d_in[9];
    float* out = (float*)d_out;

    char* ws = (char*)d_ws;
    uint4*  wxi = (uint4*)(ws + WXI_OFF);
    uint4*  wh8 = (uint4*)(ws + WH8_OFF);
    uint4*  wp8 = (uint4*)(ws + WP8_OFF);
    float4* blh = (float4*)(ws + BLH_OFF);
    float*  bpp = (float*)(ws + BPP_OFF);
    char*   comm = ws + COMM_OFF;

    hipMemsetAsync(comm, 0, COMM_SZ, stream);
    prep_kernel<<<512, 256, 0, stream>>>(W_x, W_h, W_p, b_lstm, b_p, wxi, wh8, wp8, blh, bpp);
    ntm_kernel<<<2*B_, 1024, 0, stream>>>(inputs, W_o, b_o, r0, w0,
                                          wxi, wh8, wp8, blh, bpp, comm, out);
}

// Round 22
// 1558.588 us; speedup vs baseline: 1.4740x; 1.0057x over previous
//
#include <hip/hip_runtime.h>
#include <math.h>

typedef _Float16 h2_t __attribute__((ext_vector_type(2)));

#define U_ 256
#define NN 128
#define MM 64
#define OUT_ 8
#define CLIPV 20.0f
#define IN_DIM_ 9
#define PP 268
#define B_ 128
#define T_ 130
#define TSTART 65

// ws element counts / byte offsets
#define NWXI 6144       // 2hf * 16wv * 3j * 64ln      (uint4 int8, K=96 pad, kb=q*12+4j)
#define NWH8 16384      // 2hf * 128g4 * 64slot(j*8+q) (uint4 int8, kb=q*32+4j)
#define NWP8 4352       // 68cg * 64slot(j*8+q)        (uint4 int8, FULL width)
#define WXI_OFF 0
#define WH8_OFF 98304
#define WP8_OFF 360448
#define BLH_OFF 430080
#define BPP_OFF 434176
#define COMM_OFF 435264
#define COMM_STRIDE 2176          // hA512|hB512|(unused)|flags|pad
#define COMM_SZ (B_*COMM_STRIDE)
#define PREP_N (NWXI + NWH8 + NWP8 + 256 + 272)

#define WSCALE 256.f
#define HSCALE 127.f
#define OSCALE (1.f/(256.f*127.f))

__device__ __forceinline__ float sigf(float x){ return 1.0f/(1.0f+__expf(-x)); }
__device__ __forceinline__ float splus(float x){ return log1pf(__expf(x)); }
__device__ __forceinline__ float clipf(float x){ return fminf(fmaxf(x,-CLIPV),CLIPV); }

#if defined(__has_builtin)
#if __has_builtin(__builtin_amdgcn_sdot4)
#define SDOT4(a,b,c) __builtin_amdgcn_sdot4((a),(b),(c),false)
#endif
#endif
#ifndef SDOT4
__device__ __forceinline__ int sdot4_sw(int a, int b, int c){
    c += (int)(signed char)(a      ) * (int)(signed char)(b      );
    c += (int)(signed char)(a >> 8 ) * (int)(signed char)(b >> 8 );
    c += (int)(signed char)(a >> 16) * (int)(signed char)(b >> 16);
    c += (a >> 24) * (b >> 24);
    return c;
}
#define SDOT4(a,b,c) sdot4_sw((a),(b),(c))
#endif

#define SD4(u, hw) { \
    a0 = SDOT4((int)(u).x, hw, a0); a1 = SDOT4((int)(u).y, hw, a1); \
    a2 = SDOT4((int)(u).z, hw, a2); a3 = SDOT4((int)(u).w, hw, a3); }
#define SD4P(u, hw) { \
    pa0 = SDOT4((int)(u).x, hw, pa0); pa1 = SDOT4((int)(u).y, hw, pa1); \
    pa2 = SDOT4((int)(u).z, hw, pa2); pa3 = SDOT4((int)(u).w, hw, pa3); }

// encode w -> int8 byte of round(w*256), clamped
__device__ __forceinline__ unsigned ei8(float w){
    int v = (int)rintf(w * WSCALE);
    v = v < -127 ? -127 : (v > 127 ? 127 : v);
    return (unsigned)(v & 0xFF);
}

__device__ __forceinline__ unsigned packi8x4(float a, float b, float c, float d){
    int va = (int)rintf(a * HSCALE); va = va < -127 ? -127 : (va > 127 ? 127 : va);
    int vb = (int)rintf(b * HSCALE); vb = vb < -127 ? -127 : (vb > 127 ? 127 : vb);
    int vc = (int)rintf(c * HSCALE); vc = vc < -127 ? -127 : (vc > 127 ? 127 : vc);
    int vd = (int)rintf(d * HSCALE); vd = vd < -127 ? -127 : (vd > 127 ? 127 : vd);
    return (va & 0xFF) | ((vb & 0xFF) << 8) | ((vc & 0xFF) << 16) | ((vd & 0xFF) << 24);
}

__global__ void prep_kernel(const float* __restrict__ W_x, const float* __restrict__ W_h,
                            const float* __restrict__ W_p, const float* __restrict__ b_lstm,
                            const float* __restrict__ b_p,
                            uint4* __restrict__ wxi8, uint4* __restrict__ whi8,
                            uint4* __restrict__ wpi8,
                            float4* __restrict__ blh, float* __restrict__ bpp)
{
    for (int idx = blockIdx.x*blockDim.x + threadIdx.x; idx < PREP_N; idx += gridDim.x*blockDim.x){
        if (idx < NWXI){
            // int8 wx, ctrl order [r(64), x(9), pad]: [hf][wv][j][ln], kb=q*12+4j (K=96)
            int hf = idx/3072, rem = idx - hf*3072;
            int wv = rem/192, r2 = rem - wv*192, j = r2>>6, ln = r2&63;
            int g4 = wv*8 + (ln>>3), q = ln&7, kb = q*12 + 4*j;
            unsigned c[4];
            #pragma unroll
            for (int g=0; g<4; ++g){
                int col = g*256 + hf*128 + g4;
                unsigned w = 0;
                #pragma unroll
                for (int k=0; k<4; ++k){
                    int K = kb+k;
                    float f = (K<64) ? W_x[(9+K)*1024+col] : (K<73 ? W_x[(K-64)*1024+col] : 0.f);
                    w |= ei8(f) << (8*k);
                }
                c[g] = w;
            }
            wxi8[idx] = make_uint4(c[0],c[1],c[2],c[3]);
        } else if (idx < NWXI + NWH8){
            // int8 W_h: [hf][g4][slot j*8+q], kb=q*32+4j
            int e = idx - NWXI;
            int hf = e>>13, rem = e&8191, g4 = rem>>6, s = rem&63;
            int j = s>>3, q = s&7, kb = q*32 + 4*j;
            unsigned c[4];
            #pragma unroll
            for (int g=0; g<4; ++g){
                int col = g*256 + hf*128 + g4;
                c[g] = ei8(W_h[(kb+0)*1024+col])
                     | (ei8(W_h[(kb+1)*1024+col]) << 8)
                     | (ei8(W_h[(kb+2)*1024+col]) << 16)
                     | (ei8(W_h[(kb+3)*1024+col]) << 24);
            }
            whi8[e] = make_uint4(c[0],c[1],c[2],c[3]);
        } else if (idx < NWXI + NWH8 + NWP8){
            // int8 W_p FULL width: [cg][slot j*8+q], kb=q*32+4j
            int e = idx - NWXI - NWH8;
            int cg = e>>6, s = e&63;
            int j = s>>3, q = s&7, kb = q*32 + 4*j;
            unsigned c[4];
            #pragma unroll
            for (int g=0; g<4; ++g){
                int cl = cg*4+g;
                if (cl < PP){
                    c[g] = ei8(W_p[(kb+0)*PP+cl])
                         | (ei8(W_p[(kb+1)*PP+cl]) << 8)
                         | (ei8(W_p[(kb+2)*PP+cl]) << 16)
                         | (ei8(W_p[(kb+3)*PP+cl]) << 24);
                } else c[g] = 0u;
            }
            wpi8[e] = make_uint4(c[0],c[1],c[2],c[3]);
        } else if (idx < NWXI + NWH8 + NWP8 + 256){
            int u = idx - NWXI - NWH8 - NWP8;
            blh[u] = make_float4(b_lstm[u], b_lstm[256+u], b_lstm[512+u], b_lstm[768+u]);
        } else {
            int j = idx - NWXI - NWH8 - NWP8 - 256;
            bpp[j] = (j < PP) ? b_p[j] : 0.f;
        }
    }
}

__device__ __forceinline__ float decodeP(int rc, float p){
    if (rc < 64 || (rc >= 70 && rc < 134) || rc >= 204) return tanhf(p);
    if (rc >= 140 && rc < 204) return sigf(p);
    return p;
}

__global__ __launch_bounds__(1024,1) void ntm_kernel(
    const float* __restrict__ inputs,
    const float* __restrict__ W_o, const float* __restrict__ b_o,
    const float* __restrict__ r0, const float* __restrict__ w0,
    const uint4* __restrict__ wxi8, const uint4* __restrict__ whi8,
    const uint4* __restrict__ wpi8,
    const float4* __restrict__ blh, const float* __restrict__ bpp,
    char* comm, float* __restrict__ out)
{
    const int bid = blockIdx.x, hf = bid>>7, b = bid&127;
    const int t = threadIdx.x, wv = t>>6, ln = t&63;
    const int g4 = t>>3, q = t&7;

    char* cb = comm + b*COMM_STRIDE;
    volatile float* hOwn = (volatile float*)(cb + hf*512);
    volatile float* hOth = (volatile float*)(cb + (hf^1)*512);
    volatile int*   flg  = (volatile int*)(cb + 2112);   // [f1A,f1B]

    __shared__ uint4 wxL8[3072];         // 48KB pinned int8 wx half (conflict-free)
    __shared__ uint4 whL8[4][1024];      // 64KB pinned int8 W_h slices j=0..3
    __shared__ float Mem[NN][MM+1];
    __shared__ float4 gpart4[128];
    __shared__ float4 blhL[128];
    __shared__ float hbuf[U_];
    __shared__ float cbuf[128];
    __shared__ unsigned hq[64];          // h as int8 x4 words
    __shared__ unsigned xq[24];          // ctrl [r(16w), x(3w), pad(5w)] int8
    __shared__ float prmS[12];
    __shared__ float scal[12];
    __shared__ float kv[2][MM], ebuf[MM], abuf[MM];
    __shared__ float innr[2][NN], Mn[NN], wgs[2][NN], wtab[2][NN];
    __shared__ float rpart[16][MM];
    __shared__ float jpart[OUT_];

    // ---- init ----
    for (int i=t; i<3072; i+=1024) wxL8[i] = wxi8[hf*3072 + i];
    for (int i=t; i<4096; i+=1024){
        int j = i>>10, jj = i&1023;
        whL8[j][jj] = whi8[hf*8192 + (jj>>3)*64 + j*8 + (jj&7)];
    }
    for (int i=t; i<NN*MM; i+=1024) Mem[i>>6][i&63] = 1e-6f;
    if (t < 128){
        gpart4[t] = make_float4(0.f,0.f,0.f,0.f);
        blhL[t] = blh[hf*128+t];
        cbuf[t] = 0.f;
        Mn[t] = 8e-6f;
    }
    if (t < 64) hq[t] = 0u;
    if (t < U_) hbuf[t] = 0.f;
    if (t >= 128 && t < 256){  // wtab = softmax(w0)
        int h = (t-128)>>6, l = t&63;
        float v0 = w0[h*NN + l], v1 = w0[h*NN + l + 64];
        float mx = fmaxf(v0,v1);
        for (int off=32; off>=1; off>>=1) mx = fmaxf(mx, __shfl_xor(mx, off));
        float e0 = __expf(v0-mx), e1 = __expf(v1-mx);
        float s = e0+e1;
        for (int off=32; off>=1; off>>=1) s += __shfl_xor(s, off);
        wtab[h][l] = e0/s; wtab[h][l+64] = e1/s;
    }
    if (t >= 256 && t < 280){   // xq init: [r(16w from tanh r0), x(3w step0), zero]
        int p = t-256;
        if (p < 16){
            xq[p] = packi8x4(tanhf(r0[4*p]), tanhf(r0[4*p+1]), tanhf(r0[4*p+2]), tanhf(r0[4*p+3]));
        } else if (p < 19){
            const float* xin = inputs + b*T_*IN_DIM_;
            int e0 = 4*(p-16);
            float f0 = (e0+0<IN_DIM_) ? xin[e0+0] : 0.f;
            float f1 = (e0+1<IN_DIM_) ? xin[e0+1] : 0.f;
            float f2 = (e0+2<IN_DIM_) ? xin[e0+2] : 0.f;
            float f3 = (e0+3<IN_DIM_) ? xin[e0+3] : 0.f;
            xq[p] = packi8x4(f0,f1,f2,f3);
        } else xq[p] = 0u;
    }
    __syncthreads();

    for (int step=0; step<T_; ++step){
        const int* xqi = (const int*)xq;

        // ---- B: gates = xq . wxL8 (int8 sdot4) + gpart + bias, fused LSTM ----
        {
            const uint4* wb = wxL8 + wv*192;
            int a0=0,a1=0,a2=0,a3=0;
            #pragma unroll
            for (int j=0; j<3; ++j){
                uint4 u = wb[j*64 + ln];
                int xw = xqi[q*3+j];
                SD4(u, xw);
            }
            #pragma unroll
            for (int m=1; m<8; m<<=1){
                a0 += __shfl_xor(a0,m); a1 += __shfl_xor(a1,m);
                a2 += __shfl_xor(a2,m); a3 += __shfl_xor(a3,m);
            }
            if (q==0){
                float4 bb = blhL[g4]; float4 gp = gpart4[g4];
                float gi=a0*OSCALE+bb.x+gp.x, gf=a1*OSCALE+bb.y+gp.y;
                float gg=a2*OSCALE+bb.z+gp.z, go=a3*OSCALE+bb.w+gp.w;
                float c = sigf(gf)*cbuf[g4] + sigf(gi)*tanhf(gg);
                cbuf[g4] = c;
                float h = sigf(go)*tanhf(c);
                hbuf[hf*128+g4] = h;
                hOwn[g4] = h;
            }
        }
        __syncthreads();                          // drains volatile h stores
        if (t==0){
            flg[hf] = step+1;
            while (flg[hf^1] < step+1) __builtin_amdgcn_s_sleep(2);
        }
        __syncthreads();
        // pull partner h; pack int8 h words
        if (t < 128){
            hbuf[(hf^1)*128 + t] = hOth[t];
        } else if (t < 160){
            const int jj = t-128;                  // own half word
            const float* hp = &hbuf[hf*128 + 4*jj];
            hq[hf*32 + jj] = packi8x4(hp[0], hp[1], hp[2], hp[3]);
        } else if (t < 192){
            const int jj = t-160;                  // partner half word (from comm)
            float h0 = hOth[4*jj], h1 = hOth[4*jj+1], h2 = hOth[4*jj+2], h3 = hOth[4*jj+3];
            hq[(hf^1)*32 + jj] = packi8x4(h0, h1, h2, h3);
        }
        __syncthreads();

        const int* hqi = (const int*)hq;

        // ---- FUSED: gpart (4 LDS + 4 streamed) ; params int8 FULL ; Mn ; jpart ; x-pre ----
        {
            const uint4* wrow = whi8 + hf*8192 + g4*64;
            int a0=0,a1=0,a2=0,a3=0;
            uint4 s4 = wrow[32+q], s5 = wrow[40+q], s6 = wrow[48+q], s7 = wrow[56+q];
            uint4 l0 = whL8[0][t], l1 = whL8[1][t], l2 = whL8[2][t], l3 = whL8[3][t];
            int hw0=hqi[q*8+0], hw1=hqi[q*8+1], hw2=hqi[q*8+2], hw3=hqi[q*8+3];
            int hw4=hqi[q*8+4], hw5=hqi[q*8+5], hw6=hqi[q*8+6], hw7=hqi[q*8+7];
            SD4(l0, hw0); SD4(l1, hw1);
            SD4(l2, hw2); SD4(l3, hw3);
            SD4(s4, hw4); SD4(s5, hw5);
            SD4(s6, hw6); SD4(s7, hw7);
            #pragma unroll
            for (int m=1; m<8; m<<=1){
                a0 += __shfl_xor(a0,m); a1 += __shfl_xor(a1,m);
                a2 += __shfl_xor(a2,m); a3 += __shfl_xor(a3,m);
            }
            if (q==0) gpart4[g4] = make_float4(a0*OSCALE, a1*OSCALE, a2*OSCALE, a3*OSCALE);
        }
        if (t < 544){
            const int cg = t>>3, qq = t&7;
            const uint4* wrow = wpi8 + cg*64;
            int pa0=0, pa1=0, pa2=0, pa3=0;
            uint4 u0=wrow[0*8+qq], u1=wrow[1*8+qq], u2=wrow[2*8+qq], u3=wrow[3*8+qq];
            uint4 u4=wrow[4*8+qq], u5=wrow[5*8+qq], u6=wrow[6*8+qq], u7=wrow[7*8+qq];
            int hw0=hqi[qq*8+0], hw1=hqi[qq*8+1], hw2=hqi[qq*8+2], hw3=hqi[qq*8+3];
            int hw4=hqi[qq*8+4], hw5=hqi[qq*8+5], hw6=hqi[qq*8+6], hw7=hqi[qq*8+7];
            SD4P(u0, hw0); SD4P(u1, hw1);
            SD4P(u2, hw2); SD4P(u3, hw3);
            SD4P(u4, hw4); SD4P(u5, hw5);
            SD4P(u6, hw6); SD4P(u7, hw7);
            #pragma unroll
            for (int m=1; m<8; m<<=1){
                pa0 += __shfl_xor(pa0,m); pa1 += __shfl_xor(pa1,m);
                pa2 += __shfl_xor(pa2,m); pa3 += __shfl_xor(pa3,m);
            }
            if (qq==0){
                #pragma unroll
                for (int j=0; j<4; ++j){
                    int aj = (j==0)?pa0:((j==1)?pa1:((j==2)?pa2:pa3));
                    int cl = cg*4+j;
                    if (cl < PP){
                        float pv = clipf(aj*OSCALE + bpp[cl]);
                        float dv = decodeP(cl, pv);
                        if (cl < 64) kv[0][cl] = dv;
                        else if (cl < 70) prmS[cl-64] = dv;
                        else if (cl < 134) kv[1][cl-70] = dv;
                        else if (cl < 140) prmS[6+cl-134] = dv;
                        else if (cl < 204) ebuf[cl-140] = dv;
                        else abuf[cl-204] = dv;
                    }
                }
            }
        } else if (t < 800){
            const int idx = t-544, n = idx>>1, m0 = (idx&1)*32;
            float s = 0.f;
            #pragma unroll 8
            for (int m=m0; m<m0+32; ++m){ float v=Mem[n][m]; s=fmaf(v,v,s); }
            s += __shfl_xor(s,1);
            if (!(idx&1)) Mn[n] = sqrtf(s);
        } else if (t < 928){
            const int o = (t-800)>>4, l16 = (t-800)&15;
            float s = 0.f;
            #pragma unroll
            for (int j=0; j<16; ++j){
                const int i = l16 + (j<<4);
                s = fmaf(hbuf[i], W_o[i*OUT_ + o], s);
            }
            s += __shfl_xor(s,1); s += __shfl_xor(s,2);
            s += __shfl_xor(s,4); s += __shfl_xor(s,8);
            if (l16==0) jpart[o] = s;
        } else if (t < 931){
            if (step+1 < T_){
                const int p = t-928;                 // xq words 16..18 (x part)
                const float* xin = inputs + (b*T_ + step+1)*IN_DIM_;
                int e0 = 4*p;
                float f0 = (e0+0<IN_DIM_) ? xin[e0+0] : 0.f;
                float f1 = (e0+1<IN_DIM_) ? xin[e0+1] : 0.f;
                float f2 = (e0+2<IN_DIM_) ? xin[e0+2] : 0.f;
                float f3 = (e0+3<IN_DIM_) ? xin[e0+3] : 0.f;
                xq[16+p] = packi8x4(f0,f1,f2,f3);
            }
        }
        __syncthreads();

        // ---- F: inner products + scal decode ----
        {
            const int h = t>>9, n = (t>>2)&127, qm = t&3, m0 = qm*16;
            float s = 0.f;
            #pragma unroll 8
            for (int m=m0; m<m0+16; ++m) s = fmaf(kv[h][m], Mem[n][m], s);
            s += __shfl_xor(s,1); s += __shfl_xor(s,2);
            if (qm==0) innr[h][n] = s;
        }
        if (t < 2){
            const int h = t;
            const float* ps = prmS + 6*h;
            scal[h]   = splus(ps[0]);
            scal[2+h] = sigf(ps[1]);
            float p0=ps[2], p1=ps[3], p2=ps[4];
            float mx = fmaxf(p0, fmaxf(p1, p2));
            float e0=__expf(p0-mx), e1=__expf(p1-mx), e2=__expf(p2-mx);
            float s = e0+e1+e2;
            scal[6+3*h]=e0/s; scal[7+3*h]=e1/s; scal[8+3*h]=e2/s;
            scal[4+h] = 1.f + splus(ps[5]);
        }
        __syncthreads();

        // ---- G: key norm + content softmax + interp + shift + sharpen ----
        if (t < 128){
            const int h = t>>6, l = ln;
            float kvl = kv[h][l];
            float kn2 = kvl*kvl;
            for (int off=32; off>=1; off>>=1) kn2 += __shfl_xor(kn2, off);
            float kn = sqrtf(kn2);
            float beta = scal[h], g = scal[2+h];
            float bk0 = beta * innr[h][l]   /(kn*Mn[l]   +1e-8f);
            float bk1 = beta * innr[h][l+64]/(kn*Mn[l+64]+1e-8f);
            float mx = fmaxf(bk0,bk1);
            for (int off=32; off>=1; off>>=1) mx = fmaxf(mx, __shfl_xor(mx, off));
            float e0=__expf(bk0-mx), e1=__expf(bk1-mx);
            float s=e0+e1;
            for (int off=32; off>=1; off>>=1) s += __shfl_xor(s, off);
            float wc0=e0/s, wc1=e1/s;
            wgs[h][l]    = g*wc0 + (1.f-g)*wtab[h][l];
            wgs[h][l+64] = g*wc1 + (1.f-g)*wtab[h][l+64];
            float gamma = scal[4+h];
            float s0=scal[6+3*h], s1=scal[7+3*h], s2=scal[8+3*h];
            const int n0=l, n1=l+64;
            float wt0 = s0*wgs[h][(n0+1)&127] + s1*wgs[h][n0] + s2*wgs[h][(n0+127)&127];
            float wt1 = s0*wgs[h][(n1+1)&127] + s1*wgs[h][n1] + s2*wgs[h][(n1+127)&127];
            float wp0 = __powf(wt0, gamma), wp1 = __powf(wt1, gamma);
            float ss = wp0+wp1;
            for (int off=32; off>=1; off>>=1) ss += __shfl_xor(ss, off);
            float inv = 1.0f/(ss+1e-8f);
            wtab[h][n0] = wp0*inv; wtab[h][n1] = wp1*inv;
        }
        __syncthreads();

        // ---- H: memory write + fused read-head partials ----
        {
            const float el = ebuf[ln], al = abuf[ln];
            const int n0 = wv*8;
            float racc = 0.f;
            #pragma unroll
            for (int k=0; k<8; ++k){
                const int n = n0+k;
                float ww = wtab[1][n];
                float wr = wtab[0][n];
                float v = Mem[n][ln]*(1.0f - ww*el) + ww*al;
                Mem[n][ln] = v;
                racc = fmaf(wr, v, racc);
            }
            rpart[wv][ln] = racc;
        }
        __syncthreads();

        // ---- J: r finalize + output (hf==0 writes) + xq r-pack ----
        if (t < 512){
            const int o = wv;
            float rm = 0.f;
            #pragma unroll
            for (int k=0; k<16; ++k) rm += rpart[k][ln];
            float s = rm * W_o[(U_+ln)*OUT_ + o];
            for (int off=32; off>=1; off>>=1) s += __shfl_xor(s, off);
            if (ln==0 && hf==0 && step>=TSTART){
                float logit = clipf(s + jpart[o] + b_o[o]);
                out[((b*(T_-TSTART)) + (step-TSTART))*OUT_ + o] = sigf(logit);
            }
        } else if (t < 576){
            float rm = 0.f;
            #pragma unroll
            for (int k=0; k<16; ++k) rm += rpart[k][ln];
            float r1 = __shfl_down(rm, 1);
            float r2 = __shfl_down(rm, 2);
            float r3 = __shfl_down(rm, 3);
            if (!(ln&3)) xq[ln>>2] = packi8x4(rm, r1, r2, r3);
        }
        __syncthreads();
    }
}

extern "C" void kernel_launch(void* const* d_in, const int* in_sizes, int n_in,
                              void* d_out, int out_size, void* d_ws, size_t ws_size,
                              hipStream_t stream) {
    const float* inputs = (const float*)d_in[0];
    const float* W_x    = (const float*)d_in[1];
    const float* W_h    = (const float*)d_in[2];
    const float* b_lstm = (const float*)d_in[3];
    const float* W_p    = (const float*)d_in[4];
    const float* b_p    = (const float*)d_in[5];
    const float* W_o    = (const float*)d_in[6];
    const float* b_o    = (const float*)d_in[7];
    const float* r0     = (const float*)d_in[8];
    const float* w0     = (const float*)d_in[9];
    float* out = (float*)d_out;

    char* ws = (char*)d_ws;
    uint4*  wxi = (uint4*)(ws + WXI_OFF);
    uint4*  wh8 = (uint4*)(ws + WH8_OFF);
    uint4*  wp8 = (uint4*)(ws + WP8_OFF);
    float4* blh = (float4*)(ws + BLH_OFF);
    float*  bpp = (float*)(ws + BPP_OFF);
    char*   comm = ws + COMM_OFF;

    hipMemsetAsync(comm, 0, COMM_SZ, stream);
    prep_kernel<<<512, 256, 0, stream>>>(W_x, W_h, W_p, b_lstm, b_p, wxi, wh8, wp8, blh, bpp);
    ntm_kernel<<<2*B_, 1024, 0, stream>>>(inputs, W_o, b_o, r0, w0,
                                          wxi, wh8, wp8, blh, bpp, comm, out);
}